// Round 6
// baseline (397.115 us; speedup 1.0000x reference)
//
#include <hip/hip_runtime.h>

// YOLOv1 loss, pred/labels (B,30,7,7) fp32 -> scalar.
// R2-R9 findings: all structures (scalar gather 140us, LDS 132, LDS+vmcnt(6)
//   pipeline 134, float4 stream 124, predicated gather 134) sit at a
//   2.8-3.1 TB/s line-touch rate. R8 replay: L3-resident data runs the SAME
//   124us (FETCH~0) -> not HBM-bound. R9: 3x fewer register bytes, same time
//   -> not register-return-bound. Model: READ path ceiling ~3.15 TB/s
//   (= m13 copy's read half; LN/RMSNorm r:w halves agree). Mandatory traffic
//   386 MB -> floor ~122us. Kernel A hit 124 (98%).
// R10: full loss in the streaming regime, one pass. Thread owns 4 consecutive
//   cells (channel row = 49 floats = 12 quads + tail cell 48 @ (6,6)); all 59
//   channel reads are 16B-wide (align-4 dwordx4 via memcpy). No LDS, no
//   barriers, lines touched exactly once.

#define GRID 7
#define NCH 30
#define CPI 49                   // cells per image
#define FPI 1470                 // floats per image per tensor
#define IPT 13                   // items per image: 12 quads + 1 tail cell
#define BLK 256
#define NBLK 2048

__device__ __forceinline__ float4 ld4u(const float* p) {
    float4 v;                     // 4B-aligned wide load; HW supports it
    __builtin_memcpy(&v, p, 16);
    return v;
}
__device__ __forceinline__ float elem(const float4& v, int k) {
    return ((const float*)&v)[k]; // k is compile-time after unroll
}

__device__ __forceinline__ float iou_xyxy(float x1a, float y1a, float x2a, float y2a,
                                          float x1b, float y1b, float x2b, float y2b) {
    float iw = fmaxf(fminf(x2a, x2b) - fmaxf(x1a, x1b), 0.0f);
    float ih = fmaxf(fminf(y2a, y2b) - fmaxf(y1a, y1b), 0.0f);
    float inter = iw * ih;
    float a1 = (x2a - x1a) * (y2a - y1a);
    float a2 = (x2b - x1b) * (y2b - y1b);
    float uni = a1 + a2 - inter;
    return inter > 0.0f ? inter / uni : 0.0f;
}

// Full per-cell loss from 19 scalars (box/conf) + cls already summed.
__device__ __forceinline__ float cell_loss_s(
        float p0, float p1, float p2, float p3, float p4,
        float p5, float p6, float p7, float p8, float p9,
        float l0, float l1, float l2, float l3, float lobj,
        float l5, float l6, float l7, float l8,
        float cls, float fm, float fn) {
    const float inv_g = 1.0f / (float)GRID;

    float cx = (p0 + fm) * inv_g, cy = (p1 + fn) * inv_g;
    float b1x1 = cx - p2 * 0.5f, b1y1 = cy - p3 * 0.5f;
    float b1x2 = cx + p2 * 0.5f, b1y2 = cy + p3 * 0.5f;
    cx = (p5 + fm) * inv_g; cy = (p6 + fn) * inv_g;
    float b2x1 = cx - p7 * 0.5f, b2y1 = cy - p8 * 0.5f;
    float b2x2 = cx + p7 * 0.5f, b2y2 = cy + p8 * 0.5f;
    cx = (l0 + fm) * inv_g; cy = (l1 + fn) * inv_g;
    float gx1 = cx - l2 * 0.5f, gy1 = cy - l3 * 0.5f;
    float gx2 = cx + l2 * 0.5f, gy2 = cy + l3 * 0.5f;

    float iou1 = iou_xyxy(b1x1, b1y1, b1x2, b1y2, gx1, gy1, gx2, gy2);
    float iou2 = iou_xyxy(b2x1, b2y1, b2x2, b2y2, gx1, gy1, gx2, gy2);
    bool resp1 = iou1 >= iou2;

    float dx = p0 - l0, dy = p1 - l1;
    float dw = sqrtf(p2) - sqrtf(l2), dh = sqrtf(p3) - sqrtf(l3);
    float coor1 = 5.0f * (dx * dx + dy * dy + dw * dw + dh * dh);
    dx = p5 - l5; dy = p6 - l6;
    dw = sqrtf(p7) - sqrtf(l7); dh = sqrtf(p8) - sqrtf(l8);
    float coor2 = 5.0f * (dx * dx + dy * dy + dw * dw + dh * dh);

    float e1 = p4 - iou1, e2 = p9 - iou2;
    float loss_b1 = coor1 + e1 * e1 + 0.5f * e2 * e2;
    float loss_b2 = coor2 + e2 * e2 + 0.5f * e1 * e1;

    float obj_loss = (resp1 ? loss_b1 : loss_b2) + cls;
    float noobj_loss = 0.5f * (p4 * p4 + p9 * p9);
    return (lobj == 1.0f) ? obj_loss : noobj_loss;
}

__device__ __forceinline__ void block_reduce_write(float acc, float* dst) {
    #pragma unroll
    for (int off = 32; off > 0; off >>= 1)
        acc += __shfl_down(acc, off, 64);
    __shared__ float rsm[4];
    int lane = threadIdx.x & 63;
    int wid = threadIdx.x >> 6;
    if (lane == 0) rsm[wid] = acc;
    __syncthreads();
    if (threadIdx.x == 0)
        dst[blockIdx.x] = rsm[0] + rsm[1] + rsm[2] + rsm[3];
}

__global__ void __launch_bounds__(BLK) yolo_partial_kernel(
        const float* __restrict__ pred,
        const float* __restrict__ labels,
        float* __restrict__ partials,
        int nitems, float invB) {
    float acc = 0.0f;
    int stride = gridDim.x * blockDim.x;

    for (int t = blockIdx.x * blockDim.x + threadIdx.x; t < nitems; t += stride) {
        int img = t / IPT;                     // magic-mul div
        int item = t - img * IPT;
        const float* pb0 = pred   + img * FPI;
        const float* lb0 = labels + img * FPI;

        if (item < 12) {
            // ---- quad path: cells c0..c0+3, all reads 16B wide ----
            int c0 = item * 4;
            const float* pb = pb0 + c0;
            const float* lb = lb0 + c0;

            float4 P[10], L[9];
            #pragma unroll
            for (int c = 0; c < 10; ++c) P[c] = ld4u(pb + c * CPI);
            #pragma unroll
            for (int c = 0; c < 9; ++c)  L[c] = ld4u(lb + c * CPI);

            float4 cls4 = make_float4(0.f, 0.f, 0.f, 0.f);
            #pragma unroll
            for (int c = 10; c < NCH; ++c) {
                float4 pv = ld4u(pb + c * CPI);
                float4 lv = ld4u(lb + c * CPI);
                float dx = pv.x - lv.x, dy = pv.y - lv.y;
                float dz = pv.z - lv.z, dw = pv.w - lv.w;
                cls4.x += dx * dx; cls4.y += dy * dy;
                cls4.z += dz * dz; cls4.w += dw * dw;
            }

            #pragma unroll
            for (int k = 0; k < 4; ++k) {
                int cell = c0 + k;
                int m = cell / GRID;
                int n = cell - m * GRID;
                acc += cell_loss_s(
                    elem(P[0],k), elem(P[1],k), elem(P[2],k), elem(P[3],k), elem(P[4],k),
                    elem(P[5],k), elem(P[6],k), elem(P[7],k), elem(P[8],k), elem(P[9],k),
                    elem(L[0],k), elem(L[1],k), elem(L[2],k), elem(L[3],k), elem(L[4],k),
                    elem(L[5],k), elem(L[6],k), elem(L[7],k), elem(L[8],k),
                    elem(cls4,k), (float)m, (float)n);
            }
        } else {
            // ---- tail path: cell 48, (m,n) = (6,6), scalar loads ----
            const float* pb = pb0 + 48;
            const float* lb = lb0 + 48;
            float cls = 0.0f;
            #pragma unroll
            for (int c = 10; c < NCH; ++c) {
                float d = pb[c * CPI] - lb[c * CPI];
                cls += d * d;
            }
            acc += cell_loss_s(
                pb[0*CPI], pb[1*CPI], pb[2*CPI], pb[3*CPI], pb[4*CPI],
                pb[5*CPI], pb[6*CPI], pb[7*CPI], pb[8*CPI], pb[9*CPI],
                lb[0*CPI], lb[1*CPI], lb[2*CPI], lb[3*CPI], lb[4*CPI],
                lb[5*CPI], lb[6*CPI], lb[7*CPI], lb[8*CPI],
                cls, 6.0f, 6.0f);
        }
    }
    block_reduce_write(acc * invB, partials);
}

__global__ void __launch_bounds__(256) yolo_final_kernel(
        const float* __restrict__ partials, float* __restrict__ out, int np) {
    float acc = 0.0f;
    for (int i = threadIdx.x; i < np; i += 256)
        acc += partials[i];
    #pragma unroll
    for (int off = 32; off > 0; off >>= 1)
        acc += __shfl_down(acc, off, 64);
    __shared__ float rsm[4];
    int lane = threadIdx.x & 63;
    int wid = threadIdx.x >> 6;
    if (lane == 0) rsm[wid] = acc;
    __syncthreads();
    if (threadIdx.x == 0)
        out[0] = rsm[0] + rsm[1] + rsm[2] + rsm[3];
}

extern "C" void kernel_launch(void* const* d_in, const int* in_sizes, int n_in,
                              void* d_out, int out_size, void* d_ws, size_t ws_size,
                              hipStream_t stream) {
    const float* pred = (const float*)d_in[0];
    const float* labels = (const float*)d_in[1];
    float* out = (float*)d_out;
    float* partials = (float*)d_ws;

    int total = in_sizes[0];           // element count per tensor
    int B = total / FPI;               // 32768
    if (B <= 0) return;
    float invB = 1.0f / (float)B;
    int nitems = B * IPT;              // 425,984

    int nblk = NBLK;
    size_t cap = ws_size / sizeof(float);
    if ((size_t)nblk > cap) nblk = (int)cap > 0 ? (int)cap : 1;

    yolo_partial_kernel<<<nblk, BLK, 0, stream>>>(pred, labels, partials,
                                                  nitems, invB);
    yolo_final_kernel<<<1, 256, 0, stream>>>(partials, out, nblk);
}

// Round 7
// 378.728 us; speedup vs baseline: 1.0485x; 1.0485x over previous
//
#include <hip/hip_runtime.h>

// YOLOv1 loss, pred/labels (B,30,7,7) fp32 -> scalar.
// FINAL (R11 = revert to R6, the best measured structure: bench 380.9us).
//
// Measured invariant (R2-R10, six structures): duration = (mandatory 64B
// line touches) x 12.6-13.6 cyc/line/CU, regardless of load width (4B vs
// 16B), destination (VGPR vs LDS via global_load_lds), source residency
// (HBM vs fully-L3-resident: R8 replay rows FETCH~0 ran the SAME time),
// register-return bytes (R9: 3x fewer, same time), or pipelining (R7
// counted-vmcnt = R6 drain). The CU line-fill path sustains ~5 B/cyc/CU
// (~3.1 TB/s chip = read half of the 6.29 TB/s copy ubench). Floor for
// 386 MB = ~122us; pure stream (R8-A) hit 124 but can't compute the
// channel->cell transpose; both bridges measured net-negative:
//   - second gather pass over ch0-9 (R8): +20us total
//   - misaligned dwordx4 gather (R10): +10us (line straddle, 196%16=4)
// This kernel: full-tensor LDS staging at width 16 (aligned: group base
// 23520B % 16 == 0), compute from LDS, 13.4 cyc/line = 6% over floor.

#define GRID 7
#define NCH 30
#define CPI (GRID * GRID)        // 49 cells per image
#define FPI (NCH * CPI)          // 1470 floats per image per tensor
#define IPB 4                    // images per group (group base 16B-aligned)
#define BLK 256
#define CELLS_PB (IPB * CPI)     // 196 cells computed per group
#define F_PB (IPB * FPI)         // 5880 floats per tensor per group
#define F4_PB (F_PB / 4)         // 1470 float4 per tensor per group
#define FALLBACK_NBLK 2048

typedef const __attribute__((address_space(1))) void gvoid_t;
typedef __attribute__((address_space(3))) void lvoid_t;

__device__ __forceinline__ float iou_xyxy(float x1a, float y1a, float x2a, float y2a,
                                          float x1b, float y1b, float x2b, float y2b) {
    float iw = fmaxf(fminf(x2a, x2b) - fmaxf(x1a, x1b), 0.0f);
    float ih = fmaxf(fminf(y2a, y2b) - fmaxf(y1a, y1b), 0.0f);
    float inter = iw * ih;
    float a1 = (x2a - x1a) * (y2a - y1a);
    float a2 = (x2b - x1b) * (y2b - y1b);
    float uni = a1 + a2 - inter;
    return inter > 0.0f ? inter / uni : 0.0f;
}

// pb/lb point at this cell's element of channel 0; channel c lives at +c*CPI.
__device__ __forceinline__ float cell_loss(const float* __restrict__ pb,
                                           const float* __restrict__ lb,
                                           float fm, float fn) {
    float p0 = pb[0 * CPI], p1 = pb[1 * CPI], p2 = pb[2 * CPI], p3 = pb[3 * CPI];
    float p4 = pb[4 * CPI], p5 = pb[5 * CPI], p6 = pb[6 * CPI], p7 = pb[7 * CPI];
    float p8 = pb[8 * CPI], p9 = pb[9 * CPI];
    float l0 = lb[0 * CPI], l1 = lb[1 * CPI], l2 = lb[2 * CPI], l3 = lb[3 * CPI];
    float lobj = lb[4 * CPI];
    float l5 = lb[5 * CPI], l6 = lb[6 * CPI], l7 = lb[7 * CPI], l8 = lb[8 * CPI];

    float cls = 0.0f;
    #pragma unroll
    for (int c = 10; c < NCH; ++c) {
        float d = pb[c * CPI] - lb[c * CPI];
        cls += d * d;
    }

    const float inv_g = 1.0f / (float)GRID;

    float cx = (p0 + fm) * inv_g, cy = (p1 + fn) * inv_g;
    float b1x1 = cx - p2 * 0.5f, b1y1 = cy - p3 * 0.5f;
    float b1x2 = cx + p2 * 0.5f, b1y2 = cy + p3 * 0.5f;
    cx = (p5 + fm) * inv_g; cy = (p6 + fn) * inv_g;
    float b2x1 = cx - p7 * 0.5f, b2y1 = cy - p8 * 0.5f;
    float b2x2 = cx + p7 * 0.5f, b2y2 = cy + p8 * 0.5f;
    cx = (l0 + fm) * inv_g; cy = (l1 + fn) * inv_g;
    float gx1 = cx - l2 * 0.5f, gy1 = cy - l3 * 0.5f;
    float gx2 = cx + l2 * 0.5f, gy2 = cy + l3 * 0.5f;

    float iou1 = iou_xyxy(b1x1, b1y1, b1x2, b1y2, gx1, gy1, gx2, gy2);
    float iou2 = iou_xyxy(b2x1, b2y1, b2x2, b2y2, gx1, gy1, gx2, gy2);
    bool resp1 = iou1 >= iou2;

    float dx = p0 - l0, dy = p1 - l1;
    float dw = sqrtf(p2) - sqrtf(l2), dh = sqrtf(p3) - sqrtf(l3);
    float coor1 = 5.0f * (dx * dx + dy * dy + dw * dw + dh * dh);
    dx = p5 - l5; dy = p6 - l6;
    dw = sqrtf(p7) - sqrtf(l7); dh = sqrtf(p8) - sqrtf(l8);
    float coor2 = 5.0f * (dx * dx + dy * dy + dw * dw + dh * dh);

    float e1 = p4 - iou1, e2 = p9 - iou2;
    float loss_b1 = coor1 + e1 * e1 + 0.5f * e2 * e2;
    float loss_b2 = coor2 + e2 * e2 + 0.5f * e1 * e1;

    float obj_loss = (resp1 ? loss_b1 : loss_b2) + cls;
    float noobj_loss = 0.5f * (p4 * p4 + p9 * p9);

    return (lobj == 1.0f) ? obj_loss : noobj_loss;
}

__global__ void __launch_bounds__(BLK) yolo_partial_kernel(
        const float* __restrict__ pred,
        const float* __restrict__ labels,
        float* __restrict__ partials,
        int ngroups, float invB) {
    // 2 x 23520 B = 47040 B LDS -> 3 blocks/CU: other blocks' staging
    // overlaps this block's drain+compute, keeping the line-fill path busy.
    __shared__ __align__(16) float sp[F_PB];
    __shared__ __align__(16) float sl[F_PB];

    float acc = 0.0f;

    for (int g = blockIdx.x; g < ngroups; g += gridDim.x) {
        const float* gp = pred   + (size_t)g * F_PB;   // byte off g*23520, 16B-aligned
        const float* gl = labels + (size_t)g * F_PB;

        // Stage: lane l's lds_ptr = uniform base + l*16 — matches the
        // global_load_lds HW contract. 1024 B per wave-instruction.
        for (int j = threadIdx.x; j < F4_PB; j += BLK)
            __builtin_amdgcn_global_load_lds((gvoid_t*)(gp + 4 * j),
                                             (lvoid_t*)(sp + 4 * j), 16, 0, 0);
        for (int j = threadIdx.x; j < F4_PB; j += BLK)
            __builtin_amdgcn_global_load_lds((gvoid_t*)(gl + 4 * j),
                                             (lvoid_t*)(sl + 4 * j), 16, 0, 0);

        asm volatile("s_waitcnt vmcnt(0)" ::: "memory");
        __syncthreads();

        int t = threadIdx.x;
        if (t < CELLS_PB) {
            int i = t / CPI;
            int cell = t - i * CPI;
            int m = cell / GRID;          // dim-2 index, pairs with x
            int n = cell - m * GRID;      // dim-3 index, pairs with y
            // all 59 channel reads: ds_read_b32 with immediate offset c*196B
            acc += cell_loss(&sp[i * FPI + cell], &sl[i * FPI + cell],
                             (float)m, (float)n) * invB;
        }
        __syncthreads();                  // WAR: LDS reused next group
    }

    // block reduction: wave shuffle -> LDS -> one partial write (no atomics)
    #pragma unroll
    for (int off = 32; off > 0; off >>= 1)
        acc += __shfl_down(acc, off, 64);

    __shared__ float rsm[4];
    int lane = threadIdx.x & 63;
    int wid = threadIdx.x >> 6;
    if (lane == 0) rsm[wid] = acc;
    __syncthreads();
    if (threadIdx.x == 0)
        partials[blockIdx.x] = rsm[0] + rsm[1] + rsm[2] + rsm[3];
}

__global__ void __launch_bounds__(256) yolo_final_kernel(
        const float* __restrict__ partials, int np,
        const float* __restrict__ pred, const float* __restrict__ labels,
        int b0, int B, float invB, float* __restrict__ out) {
    float acc = 0.0f;
    for (int i = threadIdx.x; i < np; i += 256)
        acc += partials[i];

    // remainder images (B % IPB), scalar path — 0 cells for B=32768
    int remcells = (B - b0) * CPI;
    for (int idx = threadIdx.x; idx < remcells; idx += 256) {
        int b = b0 + idx / CPI;
        int cell = idx % CPI;
        int m = cell / GRID;
        int n = cell - m * GRID;
        acc += cell_loss(pred + (size_t)b * FPI + cell,
                         labels + (size_t)b * FPI + cell,
                         (float)m, (float)n) * invB;
    }

    #pragma unroll
    for (int off = 32; off > 0; off >>= 1)
        acc += __shfl_down(acc, off, 64);
    __shared__ float rsm[4];
    int lane = threadIdx.x & 63;
    int wid = threadIdx.x >> 6;
    if (lane == 0) rsm[wid] = acc;
    __syncthreads();
    if (threadIdx.x == 0)
        out[0] = rsm[0] + rsm[1] + rsm[2] + rsm[3];
}

extern "C" void kernel_launch(void* const* d_in, const int* in_sizes, int n_in,
                              void* d_out, int out_size, void* d_ws, size_t ws_size,
                              hipStream_t stream) {
    const float* pred = (const float*)d_in[0];
    const float* labels = (const float*)d_in[1];
    float* out = (float*)d_out;
    float* partials = (float*)d_ws;

    int total = in_sizes[0];           // element count
    int B = total / FPI;               // 32768
    if (B <= 0) return;
    float invB = 1.0f / (float)B;
    int ngroups = B / IPB;             // 8192
    int b0 = ngroups * IPB;            // remainder start image

    // one-shot blocks if workspace holds ngroups partials, else grid-stride
    int nblk = ngroups;
    if (ngroups == 0) {
        nblk = 1;
    } else if ((size_t)ngroups * sizeof(float) > ws_size) {
        nblk = (ngroups < FALLBACK_NBLK) ? ngroups : FALLBACK_NBLK;
    }

    yolo_partial_kernel<<<nblk, BLK, 0, stream>>>(pred, labels, partials,
                                                  ngroups, invB);
    yolo_final_kernel<<<1, 256, 0, stream>>>(partials, nblk, pred, labels,
                                             b0, B, invB, out);
}